// Round 5
// baseline (203.828 us; speedup 1.0000x reference)
//
#include <hip/hip_runtime.h>
#include <hip/hip_bf16.h>

// B=8, Ct=256, Cs=128, H=W=32, S=1024, E=256, nH=8, hd=32
typedef unsigned short u16;
typedef unsigned int u32;
typedef __attribute__((ext_vector_type(8))) short short8;
typedef __attribute__((ext_vector_type(4))) float f32x4;
typedef __attribute__((ext_vector_type(4))) unsigned short u16x4;
typedef __attribute__((ext_vector_type(4))) int i32x4;

static __device__ __forceinline__ u16 f2bf(float x) {
  __hip_bfloat16 b = __float2bfloat16(x);
  return *reinterpret_cast<u16*>(&b);
}
static __device__ __forceinline__ u32 fbits(float x) {
  union { float f; u32 u; } v; v.f = x; return v.u;
}
// pack two f32 -> two truncated bf16 in one dword: low16 = lo>>16, high16 = hi>>16
static __device__ __forceinline__ u32 pk_trunc(float lo, float hi) {
  return __builtin_amdgcn_perm(fbits(hi), fbits(lo), 0x07060302u);
}

// 1/sqrt(32) * log2(e)  (exp2-based softmax)
#define QSCALE2 (0.17677669529663687f * 1.4426950408889634f)

// ---------------------------------------------------------------------------
// Prep: WqB = Wq*qscale2 (256x256 bf16), WkvB = [Wk@kv_w; Wv@kv_w] (512x128)
//       M2B = fuse_w@out_proj_w (256x256 bf16), qbias (*qscale2), bnpk {inv,off}
// ---------------------------------------------------------------------------
__global__ __launch_bounds__(256) void prep_kernel(
    const float* __restrict__ in_proj_w, const float* __restrict__ in_proj_b,
    const float* __restrict__ kv_w, const float* __restrict__ fuse_w,
    const float* __restrict__ out_proj_w, const float* __restrict__ out_proj_b,
    const float* __restrict__ gamma, const float* __restrict__ beta,
    const float* __restrict__ mean, const float* __restrict__ var,
    u16* __restrict__ WqB, u16* __restrict__ WkvB, u16* __restrict__ M2B,
    float* __restrict__ qbias, float2* __restrict__ bnpk) {
  int idx = blockIdx.x * 256 + threadIdx.x;
  if (idx < 65536) {
    WqB[idx] = f2bf(in_proj_w[idx] * QSCALE2);
  } else if (idx < 131072) {
    int i = idx - 65536;
    int m = i >> 7, c = i & 127;
    const float* wrow = in_proj_w + (size_t)(256 + m) * 256;
    float s = 0.f;
    for (int e2 = 0; e2 < 256; ++e2) s += wrow[e2] * kv_w[e2 * 128 + c];
    WkvB[i] = f2bf(s);
  } else if (idx < 196608) {
    int i = idx - 131072;
    int c = i >> 8, e2 = i & 255;
    float s = 0.f;
    for (int e = 0; e < 256; ++e)
      s += fuse_w[c * 256 + e] * out_proj_w[e * 256 + e2];
    M2B[i] = f2bf(s);
  } else if (idx < 196864) {
    int c = idx - 196608;
    float fbv = 0.f;
    for (int e = 0; e < 256; ++e) fbv += fuse_w[c * 256 + e] * out_proj_b[e];
    float inv = gamma[c] * rsqrtf(var[c] + 1e-5f);
    bnpk[c] = make_float2(inv, (fbv - mean[c]) * inv + beta[c]);
    qbias[c] = in_proj_b[c] * QSCALE2;
  }
}

// ---------------------------------------------------------------------------
// QKV projection, bf16 MFMA (R3 LDS version — measured good).
// grid (8, 12, 8): by<4 -> Q (WqB, K=256, tgt); else KV (WkvB, K=128, src).
// ---------------------------------------------------------------------------
__global__ __launch_bounds__(256, 3) void qkv_gemm(
    const float* __restrict__ tgt, const float* __restrict__ src,
    const u16* __restrict__ WqB, const u16* __restrict__ WkvB,
    const float* __restrict__ qbias, const float* __restrict__ bkv,
    u16* __restrict__ QB, u16* __restrict__ KB, u16* __restrict__ VB) {
  __shared__ __align__(16) u16 Wl[64 * 40];
  __shared__ __align__(16) u16 Xl[128 * 40];
  int b = blockIdx.z, by = blockIdx.y, n0 = blockIdx.x * 128;
  bool isQ = by < 4;
  int m0 = isQ ? by * 64 : (by - 4) * 64;
  int Kd = isQ ? 256 : 128;
  const u16* Wp = isQ ? WqB : WkvB;
  const float* Xp = isQ ? tgt + (size_t)b * 256 * 1024
                        : src + (size_t)b * 128 * 1024;
  int t = threadIdx.x, wave = t >> 6, lane = t & 63;
  int lq = lane & 15, quad = lane >> 4;
  f32x4 acc[4][2];
#pragma unroll
  for (int mt = 0; mt < 4; ++mt)
#pragma unroll
    for (int nt = 0; nt < 2; ++nt) acc[mt][nt] = (f32x4){0.f, 0.f, 0.f, 0.f};

  for (int k0 = 0; k0 < Kd; k0 += 32) {
    __syncthreads();
    {
      int row = t >> 2, seg = t & 3;
      *(short8*)&Wl[row * 40 + seg * 8] =
          *(const short8*)&Wp[(size_t)(m0 + row) * Kd + k0 + seg * 8];
    }
    for (int i = t; i < 4096; i += 256) {
      int k = i >> 7, n = i & 127;
      Xl[n * 40 + k] = f2bf(Xp[(size_t)(k0 + k) * 1024 + n0 + n]);
    }
    __syncthreads();
    short8 af[4], bf[2];
#pragma unroll
    for (int mt = 0; mt < 4; ++mt)
      af[mt] = *(const short8*)&Wl[(mt * 16 + lq) * 40 + quad * 8];
#pragma unroll
    for (int nt = 0; nt < 2; ++nt)
      bf[nt] = *(const short8*)&Xl[(wave * 32 + nt * 16 + lq) * 40 + quad * 8];
#pragma unroll
    for (int mt = 0; mt < 4; ++mt)
#pragma unroll
      for (int nt = 0; nt < 2; ++nt)
        acc[mt][nt] = __builtin_amdgcn_mfma_f32_16x16x32_bf16(af[mt], bf[nt],
                                                              acc[mt][nt], 0, 0, 0);
  }
  if (isQ) {
#pragma unroll
    for (int mt = 0; mt < 4; ++mt) {
      int e = m0 + mt * 16 + quad * 4;
      f32x4 bi = *(const f32x4*)&qbias[e];
#pragma unroll
      for (int nt = 0; nt < 2; ++nt) {
        int n = n0 + wave * 32 + nt * 16 + lq;
        u16x4 pk;
#pragma unroll
        for (int r = 0; r < 4; ++r) pk[r] = f2bf(acc[mt][nt][r] + bi[r]);
        *(u16x4*)&QB[((size_t)b * 1024 + n) * 256 + e] = pk;
      }
    }
  } else {
#pragma unroll
    for (int mt = 0; mt < 4; ++mt) {
      int m = m0 + mt * 16 + quad * 4;
      f32x4 bi = *(const f32x4*)&bkv[m];
#pragma unroll
      for (int nt = 0; nt < 2; ++nt) {
        int n = n0 + wave * 32 + nt * 16 + lq;
        if (m < 256) {
          int hh = m >> 5, d = m & 31;
          u16x4 pk;
#pragma unroll
          for (int r = 0; r < 4; ++r) pk[r] = f2bf(acc[mt][nt][r] + bi[r]);
          *(u16x4*)&KB[((size_t)(b * 8 + hh) * 1024 + n) * 32 + d] = pk;
        } else {
          int e = m - 256;
#pragma unroll
          for (int r = 0; r < 4; ++r)
            VB[((size_t)b * 256 + e + r) * 1024 + n] = f2bf(acc[mt][nt][r] + bi[r]);
        }
      }
    }
  }
}

// ---------------------------------------------------------------------------
// Barrier-free LDS-free MFMA attention (transposed-scores form).
// grid (16, 8, 8) = 1024 blocks, 4 waves x 16 queries.
// Pass A: St = K*Q^T (A=K with permuted key rows so each lane ends up holding
//         keys quad*8+{0..7} for its query lq) -> exp2 -> pack (v_perm) ->
//         O^T += V^T * P^T. l_q is a per-lane scalar.
// Pass B: untransposed S = Q*K^T for normalized column sums -> attn_map.
// ---------------------------------------------------------------------------
__global__ __launch_bounds__(256) void attn_st(
    const u16* __restrict__ QB, const u16* __restrict__ KB,
    const u16* __restrict__ VB, u16* __restrict__ ctxB,
    float* __restrict__ attn_out) {
  __shared__ float colsum[1024];
  int b = blockIdx.z, h = blockIdx.y, q0 = blockIdx.x * 64;
  int t = threadIdx.x, wave = t >> 6, lane = t & 63;
  int lq = lane & 15, quad = lane >> 4;

  const u16* Qb = QB + (size_t)b * 1024 * 256 + h * 32;
  const u16* Kb = KB + (size_t)(b * 8 + h) * 1024 * 32;
  const u16* Vb = VB + (size_t)(b * 256 + h * 32) * 1024;

  for (int i = t; i < 1024; i += 256) colsum[i] = 0.f;

  // Q fragment: identical lane layout for A- and B-operand roles.
  int myq = q0 + wave * 16 + lq;
  short8 qf = *(const short8*)(Qb + (size_t)myq * 256 + quad * 8);

  // permuted key row for St A-fragment: m -> key (m>>2)*8 + (m&3)
  int keyA = ((lq >> 2) << 3) | (lq & 3);
  const u16* KbA0 = Kb + (size_t)keyA * 32 + quad * 8;        // + c*32
  const u16* KbA1 = Kb + (size_t)(keyA + 4) * 32 + quad * 8;  // + c*32
  const u16* Vb0 = Vb + (size_t)lq * 1024 + quad * 8;         // + c
  const u16* Vb1 = Vb + (size_t)(16 + lq) * 1024 + quad * 8;  // + c

  const f32x4 zf = (f32x4){0.f, 0.f, 0.f, 0.f};
  f32x4 O0 = zf, O1 = zf;
  float lsum = 0.f;

  // ---------------- Pass A: 32 keys per iteration, no LDS, no barriers ------
#pragma unroll 2
  for (int c = 0; c < 1024; c += 32) {
    short8 kf0 = *(const short8*)(KbA0 + (size_t)c * 32);
    short8 kf1 = *(const short8*)(KbA1 + (size_t)c * 32);
    f32x4 s0 = __builtin_amdgcn_mfma_f32_16x16x32_bf16(kf0, qf, zf, 0, 0, 0);
    f32x4 s1 = __builtin_amdgcn_mfma_f32_16x16x32_bf16(kf1, qf, zf, 0, 0, 0);
    f32x4 e0, e1;
#pragma unroll
    for (int r = 0; r < 4; ++r) {
      e0[r] = exp2f(s0[r]);
      e1[r] = exp2f(s1[r]);
    }
    lsum += (e0[0] + e0[1]) + (e0[2] + e0[3]) + (e1[0] + e1[1]) + (e1[2] + e1[3]);
    // P^T B-fragment: keys quad*8+{0..7} = {e0[0..3], e1[0..3]} — lane-local.
    i32x4 pi;
    pi[0] = (int)pk_trunc(e0[0], e0[1]);
    pi[1] = (int)pk_trunc(e0[2], e0[3]);
    pi[2] = (int)pk_trunc(e1[0], e1[1]);
    pi[3] = (int)pk_trunc(e1[2], e1[3]);
    short8 pf = *(short8*)&pi;
    short8 vf0 = *(const short8*)(Vb0 + c);
    short8 vf1 = *(const short8*)(Vb1 + c);
    O0 = __builtin_amdgcn_mfma_f32_16x16x32_bf16(vf0, pf, O0, 0, 0, 0);
    O1 = __builtin_amdgcn_mfma_f32_16x16x32_bf16(vf1, pf, O1, 0, 0, 0);
  }

  // l_q: reduce the 4 quad-partials (per-lane scalar afterwards)
  lsum += __shfl_xor(lsum, 16);
  lsum += __shfl_xor(lsum, 32);
  float linv = 1.f / lsum;

  // write ctx: lane holds query lq; rows d = vd0 + quad*4 + r
  {
    u16x4 pk0, pk1;
#pragma unroll
    for (int r = 0; r < 4; ++r) {
      pk0[r] = f2bf(O0[r] * linv);
      pk1[r] = f2bf(O1[r] * linv);
    }
    u16* crow = ctxB + ((size_t)b * 1024 + myq) * 256 + h * 32 + quad * 4;
    *(u16x4*)crow = pk0;
    *(u16x4*)(crow + 16) = pk1;
  }

  // linv for Pass B's row layout (row q = quad*4+r)
  float lv[4];
#pragma unroll
  for (int r = 0; r < 4; ++r) lv[r] = __shfl(linv, quad * 4 + r);

  __syncthreads();  // colsum zero-init visible

  // ---------------- Pass B: normalized column sums (untransposed) ----------
#pragma unroll 2
  for (int c = 0; c < 1024; c += 16) {
    short8 kf = *(const short8*)(Kb + (size_t)(c + lq) * 32 + quad * 8);
    f32x4 s = __builtin_amdgcn_mfma_f32_16x16x32_bf16(qf, kf, zf, 0, 0, 0);
    float cs = exp2f(s[0]) * lv[0] + exp2f(s[1]) * lv[1] +
               exp2f(s[2]) * lv[2] + exp2f(s[3]) * lv[3];
    cs += __shfl_xor(cs, 16);
    cs += __shfl_xor(cs, 32);
    if (quad == 0) atomicAdd(&colsum[c + lq], cs);
  }
  __syncthreads();
  for (int i = t; i < 1024; i += 256)
    atomicAdd(&attn_out[b * 1024 + i], colsum[i] * (1.f / 8192.f));
}

// ---------------------------------------------------------------------------
// Fused out GEMM + BN + SiLU + residual (R3 LDS version — measured good).
// ---------------------------------------------------------------------------
__global__ __launch_bounds__(256, 3) void fused_out(
    const u16* __restrict__ M2B, const u16* __restrict__ ctxB,
    const float* __restrict__ tgt, const float2* __restrict__ bnpk,
    float* __restrict__ y) {
  __shared__ __align__(16) u16 Al[64 * 40];
  __shared__ __align__(16) u16 Bl[128 * 40];
  int b = blockIdx.z, c0 = blockIdx.y * 64, s0 = blockIdx.x * 128;
  int t = threadIdx.x, wave = t >> 6, lane = t & 63;
  int lq = lane & 15, quad = lane >> 4;
  f32x4 acc[4][2];
#pragma unroll
  for (int mt = 0; mt < 4; ++mt)
#pragma unroll
    for (int nt = 0; nt < 2; ++nt) acc[mt][nt] = (f32x4){0.f, 0.f, 0.f, 0.f};

  for (int k0 = 0; k0 < 256; k0 += 32) {
    __syncthreads();
    {
      int row = t >> 2, seg = t & 3;
      *(short8*)&Al[row * 40 + seg * 8] =
          *(const short8*)&M2B[(size_t)(c0 + row) * 256 + k0 + seg * 8];
    }
    for (int i = t; i < 512; i += 256) {
      int row = i >> 2, seg = i & 3;
      *(short8*)&Bl[row * 40 + seg * 8] =
          *(const short8*)&ctxB[((size_t)b * 1024 + s0 + row) * 256 + k0 + seg * 8];
    }
    __syncthreads();
    short8 af[4], bf[2];
#pragma unroll
    for (int mt = 0; mt < 4; ++mt)
      af[mt] = *(const short8*)&Al[(mt * 16 + lq) * 40 + quad * 8];
#pragma unroll
    for (int nt = 0; nt < 2; ++nt)
      bf[nt] = *(const short8*)&Bl[(wave * 32 + nt * 16 + lq) * 40 + quad * 8];
#pragma unroll
    for (int mt = 0; mt < 4; ++mt)
#pragma unroll
      for (int nt = 0; nt < 2; ++nt)
        acc[mt][nt] = __builtin_amdgcn_mfma_f32_16x16x32_bf16(af[mt], bf[nt],
                                                              acc[mt][nt], 0, 0, 0);
  }
#pragma unroll
  for (int mt = 0; mt < 4; ++mt) {
#pragma unroll
    for (int r = 0; r < 4; ++r) {
      int c = c0 + mt * 16 + quad * 4 + r;
      float2 p = bnpk[c];
#pragma unroll
      for (int nt = 0; nt < 2; ++nt) {
        int s = s0 + wave * 32 + nt * 16 + lq;
        float bn = acc[mt][nt][r] * p.x + p.y;
        float sig = 1.f / (1.f + __expf(-bn));
        size_t idx = ((size_t)b * 256 + c) * 1024 + s;
        y[idx] = tgt[idx] + bn * sig;
      }
    }
  }
}

// ---------------------------------------------------------------------------
extern "C" void kernel_launch(void* const* d_in, const int* in_sizes, int n_in,
                              void* d_out, int out_size, void* d_ws, size_t ws_size,
                              hipStream_t stream) {
  const float* tgt = (const float*)d_in[0];
  const float* src = (const float*)d_in[1];
  const float* kv_w = (const float*)d_in[2];
  const float* in_proj_w = (const float*)d_in[3];
  const float* in_proj_b = (const float*)d_in[4];
  const float* out_proj_w = (const float*)d_in[5];
  const float* out_proj_b = (const float*)d_in[6];
  const float* fuse_w = (const float*)d_in[7];
  const float* bn_gamma = (const float*)d_in[8];
  const float* bn_beta = (const float*)d_in[9];
  const float* bn_mean = (const float*)d_in[10];
  const float* bn_var = (const float*)d_in[11];

  char* W = (char*)d_ws;
  u16* WqB = (u16*)W;                    // 128KB
  u16* WkvB = (u16*)(W + 131072);        // 128KB
  u16* M2B = (u16*)(W + 262144);         // 128KB
  float* qbias = (float*)(W + 393216);   // 1KB
  float2* bnpk = (float2*)(W + 394240);  // 2KB
  u16* QB = (u16*)(W + 397312);          // 4MB (B,S,E)
  u16* KB = QB + 2097152;                // 4MB (B,nH,S,hd)
  u16* VB = KB + 2097152;                // 4MB (B,E,S)
  u16* ctxB = VB + 2097152;              // 4MB (B,S,E)

  float* y = (float*)d_out;
  float* attn_out = y + 2097152;

  hipMemsetAsync(attn_out, 0, 8192 * sizeof(float), stream);
  prep_kernel<<<769, 256, 0, stream>>>(in_proj_w, in_proj_b, kv_w, fuse_w,
                                       out_proj_w, out_proj_b, bn_gamma, bn_beta,
                                       bn_mean, bn_var, WqB, WkvB, M2B, qbias, bnpk);
  qkv_gemm<<<dim3(8, 12, 8), 256, 0, stream>>>(tgt, src, WqB, WkvB, qbias,
                                               in_proj_b + 256, QB, KB, VB);
  attn_st<<<dim3(16, 8, 8), 256, 0, stream>>>(QB, KB, VB, ctxB, attn_out);
  fused_out<<<dim3(8, 4, 8), 256, 0, stream>>>(M2B, ctxB, tgt, bnpk, y);
}

// Round 6
// 185.318 us; speedup vs baseline: 1.0999x; 1.0999x over previous
//
#include <hip/hip_runtime.h>
#include <hip/hip_bf16.h>

// B=8, Ct=256, Cs=128, H=W=32, S=1024, E=256, nH=8, hd=32
typedef unsigned short u16;
typedef unsigned int u32;
typedef __attribute__((ext_vector_type(8))) short short8;
typedef __attribute__((ext_vector_type(4))) float f32x4;
typedef __attribute__((ext_vector_type(4))) unsigned short u16x4;
typedef __attribute__((ext_vector_type(4))) int i32x4;

static __device__ __forceinline__ u16 f2bf(float x) {
  __hip_bfloat16 b = __float2bfloat16(x);
  return *reinterpret_cast<u16*>(&b);
}
static __device__ __forceinline__ u32 fbits(float x) {
  union { float f; u32 u; } v; v.f = x; return v.u;
}
// pack two f32 -> two truncated bf16 in one dword
static __device__ __forceinline__ u32 pk_trunc(float lo, float hi) {
  return __builtin_amdgcn_perm(fbits(hi), fbits(lo), 0x07060302u);
}

// 1/sqrt(32) * log2(e)  (exp2-based softmax)
#define QSCALE2 (0.17677669529663687f * 1.4426950408889634f)

// ---------------------------------------------------------------------------
// Prep: WqB = Wq*qscale2 (256x256 bf16), WkvB = [Wk@kv_w; Wv@kv_w] (512x128)
//       M2B = fuse_w@out_proj_w (256x256 bf16), qbias (*qscale2), bnpk {inv,off}
// ---------------------------------------------------------------------------
__global__ __launch_bounds__(256) void prep_kernel(
    const float* __restrict__ in_proj_w, const float* __restrict__ in_proj_b,
    const float* __restrict__ kv_w, const float* __restrict__ fuse_w,
    const float* __restrict__ out_proj_w, const float* __restrict__ out_proj_b,
    const float* __restrict__ gamma, const float* __restrict__ beta,
    const float* __restrict__ mean, const float* __restrict__ var,
    u16* __restrict__ WqB, u16* __restrict__ WkvB, u16* __restrict__ M2B,
    float* __restrict__ qbias, float2* __restrict__ bnpk) {
  int idx = blockIdx.x * 256 + threadIdx.x;
  if (idx < 65536) {
    WqB[idx] = f2bf(in_proj_w[idx] * QSCALE2);
  } else if (idx < 131072) {
    int i = idx - 65536;
    int m = i >> 7, c = i & 127;
    const float* wrow = in_proj_w + (size_t)(256 + m) * 256;
    float s = 0.f;
    for (int e2 = 0; e2 < 256; ++e2) s += wrow[e2] * kv_w[e2 * 128 + c];
    WkvB[i] = f2bf(s);
  } else if (idx < 196608) {
    int i = idx - 131072;
    int c = i >> 8, e2 = i & 255;
    float s = 0.f;
    for (int e = 0; e < 256; ++e)
      s += fuse_w[c * 256 + e] * out_proj_w[e * 256 + e2];
    M2B[i] = f2bf(s);
  } else if (idx < 196864) {
    int c = idx - 196608;
    float fbv = 0.f;
    for (int e = 0; e < 256; ++e) fbv += fuse_w[c * 256 + e] * out_proj_b[e];
    float inv = gamma[c] * rsqrtf(var[c] + 1e-5f);
    bnpk[c] = make_float2(inv, (fbv - mean[c]) * inv + beta[c]);
    qbias[c] = in_proj_b[c] * QSCALE2;
  }
}

// ---------------------------------------------------------------------------
// Transpose-cast: tgt (B,256,1024) f32 -> tgtT (B,1024,256) bf16
//                 src (B,128,1024) f32 -> srcT (B,1024,128) bf16
// ---------------------------------------------------------------------------
__global__ __launch_bounds__(256) void xpose(
    const float* __restrict__ tgt, const float* __restrict__ src,
    u16* __restrict__ tgtT, u16* __restrict__ srcT) {
  __shared__ u16 tile[64 * 65];
  int b = blockIdx.z, by = blockIdx.y, sb = blockIdx.x * 64;
  const float* X;
  u16* XT;
  int C, cb;
  if (by < 4) {
    X = tgt + (size_t)b * 256 * 1024;
    XT = tgtT + (size_t)b * 1024 * 256;
    C = 256;
    cb = by * 64;
  } else {
    X = src + (size_t)b * 128 * 1024;
    XT = srcT + (size_t)b * 1024 * 128;
    C = 128;
    cb = (by - 4) * 64;
  }
  int t = threadIdx.x;
  for (int i = t; i < 4096; i += 256) {
    int c = i >> 6, s = i & 63;
    tile[c * 65 + s] = f2bf(X[(size_t)(cb + c) * 1024 + sb + s]);
  }
  __syncthreads();
  for (int i = t; i < 4096; i += 256) {
    int s = i >> 6, c = i & 63;
    XT[(size_t)(sb + s) * C + cb + c] = tile[c * 65 + s];
  }
}

// ---------------------------------------------------------------------------
// QKV projection, bf16 MFMA, all-bf16 staging (m97-style light staging).
// grid (8, 12, 8): my<4 -> Q (WqB, K=256, tgtT); else KV (WkvB, K=128, srcT).
// Tile 64m x 128n; wave = 64m x 32n (acc 4x2).
// ---------------------------------------------------------------------------
__global__ __launch_bounds__(256, 4) void qkv_gemm(
    const u16* __restrict__ tgtT, const u16* __restrict__ srcT,
    const u16* __restrict__ WqB, const u16* __restrict__ WkvB,
    const float* __restrict__ qbias, const float* __restrict__ bkv,
    u16* __restrict__ QB, u16* __restrict__ KB, u16* __restrict__ VB) {
  __shared__ __align__(16) u16 Wl[64 * 40];
  __shared__ __align__(16) u16 Xl[128 * 40];
  int b = blockIdx.z, my = blockIdx.y, n0 = blockIdx.x * 128;
  bool isQ = my < 4;
  int m0 = isQ ? my * 64 : (my - 4) * 64;
  int Kd = isQ ? 256 : 128;
  const u16* Wp = isQ ? WqB : WkvB;
  const u16* Xp = isQ ? tgtT + (size_t)b * 1024 * 256
                      : srcT + (size_t)b * 1024 * 128;
  int t = threadIdx.x, wave = t >> 6, lane = t & 63;
  int lq = lane & 15, quad = lane >> 4;
  f32x4 acc[4][2];
#pragma unroll
  for (int mt = 0; mt < 4; ++mt)
#pragma unroll
    for (int nt = 0; nt < 2; ++nt) acc[mt][nt] = (f32x4){0.f, 0.f, 0.f, 0.f};

  for (int k0 = 0; k0 < Kd; k0 += 32) {
    __syncthreads();
    {  // W tile 64x32
      int row = t >> 2, seg = t & 3;
      *(short8*)&Wl[row * 40 + seg * 8] =
          *(const short8*)&Wp[(size_t)(m0 + row) * Kd + k0 + seg * 8];
    }
    for (int i = t; i < 512; i += 256) {  // X tile 128x32 (k-contiguous!)
      int row = i >> 2, seg = i & 3;
      *(short8*)&Xl[row * 40 + seg * 8] =
          *(const short8*)&Xp[(size_t)(n0 + row) * Kd + k0 + seg * 8];
    }
    __syncthreads();
    short8 af[4], bf[2];
#pragma unroll
    for (int mt = 0; mt < 4; ++mt)
      af[mt] = *(const short8*)&Wl[(mt * 16 + lq) * 40 + quad * 8];
#pragma unroll
    for (int nt = 0; nt < 2; ++nt)
      bf[nt] = *(const short8*)&Xl[(wave * 32 + nt * 16 + lq) * 40 + quad * 8];
#pragma unroll
    for (int mt = 0; mt < 4; ++mt)
#pragma unroll
      for (int nt = 0; nt < 2; ++nt)
        acc[mt][nt] = __builtin_amdgcn_mfma_f32_16x16x32_bf16(af[mt], bf[nt],
                                                              acc[mt][nt], 0, 0, 0);
  }
  if (isQ) {
#pragma unroll
    for (int mt = 0; mt < 4; ++mt) {
      int e = m0 + mt * 16 + quad * 4;
      f32x4 bi = *(const f32x4*)&qbias[e];
#pragma unroll
      for (int nt = 0; nt < 2; ++nt) {
        int n = n0 + wave * 32 + nt * 16 + lq;
        u16x4 pk;
#pragma unroll
        for (int r = 0; r < 4; ++r) pk[r] = f2bf(acc[mt][nt][r] + bi[r]);
        *(u16x4*)&QB[((size_t)b * 1024 + n) * 256 + e] = pk;
      }
    }
  } else {
#pragma unroll
    for (int mt = 0; mt < 4; ++mt) {
      int m = m0 + mt * 16 + quad * 4;
      f32x4 bi = *(const f32x4*)&bkv[m];
#pragma unroll
      for (int nt = 0; nt < 2; ++nt) {
        int n = n0 + wave * 32 + nt * 16 + lq;
        if (m < 256) {
          int hh = m >> 5, d = m & 31;
          u16x4 pk;
#pragma unroll
          for (int r = 0; r < 4; ++r) pk[r] = f2bf(acc[mt][nt][r] + bi[r]);
          *(u16x4*)&KB[((size_t)(b * 8 + hh) * 1024 + n) * 32 + d] = pk;
        } else {
          int e = m - 256;
#pragma unroll
          for (int r = 0; r < 4; ++r)
            VB[((size_t)b * 256 + e + r) * 1024 + n] = f2bf(acc[mt][nt][r] + bi[r]);
        }
      }
    }
  }
}

// ---------------------------------------------------------------------------
// Attention pass A: transposed-scores trick (register-only P) fed from
// LDS-staged K/V. K staged with PERMUTED rows so the plain frag read at
// row pair*32+lq yields keys such that lane (lq,quad) ends holding keys
// quad*8+{0..7} for query lq (ready-made P^T B-fragment).
// grid (16,8,8)=1024 blocks, 64q each, 4 waves x 16q. LDS 19KB, no atomics.
// Outputs: ctxB bf16 (B,S,E), linv_ws (B,nH,S) fp32.
// ---------------------------------------------------------------------------
__global__ __launch_bounds__(256, 4) void attn_passA(
    const u16* __restrict__ QB, const u16* __restrict__ KB,
    const u16* __restrict__ VB, u16* __restrict__ ctxB,
    float* __restrict__ linv_ws) {
  __shared__ __align__(16) u16 Klds[128 * 40];  // permuted key rows
  __shared__ __align__(16) u16 Vlds[32 * 136];  // [d][136]
  int b = blockIdx.z, h = blockIdx.y, q0 = blockIdx.x * 64;
  int t = threadIdx.x, wave = t >> 6, lane = t & 63;
  int lq = lane & 15, quad = lane >> 4;

  const u16* Qb = QB + (size_t)b * 1024 * 256 + h * 32;
  const u16* Kb = KB + (size_t)(b * 8 + h) * 1024 * 32;
  const u16* Vb = VB + (size_t)(b * 256 + h * 32) * 1024;

  int myq = q0 + wave * 16 + lq;
  short8 qf = *(const short8*)(Qb + (size_t)myq * 256 + quad * 8);

  const f32x4 zf = (f32x4){0.f, 0.f, 0.f, 0.f};
  f32x4 O0 = zf, O1 = zf;
  float lsum = 0.f;

  for (int c0 = 0; c0 < 1024; c0 += 128) {
    __syncthreads();
    // K stage, rows permuted: key j -> row pair*32 + ((j&4)?16:0)+((j>>3)&3)*4+(j&3)
    for (int i = t; i < 512; i += 256) {
      int j = i >> 2, seg = i & 3;
      int jj = j & 31, pair = j & 96;  // pair*32 = j & ~31
      int m = ((jj & 4) << 2) + (((jj >> 3) & 3) << 2) + (jj & 3);
      *(short8*)&Klds[(pair + m) * 40 + seg * 8] =
          *(const short8*)(Kb + (size_t)(c0 + j) * 32 + seg * 8);
    }
    for (int i = t; i < 512; i += 256) {
      int d = i >> 4, part = i & 15;
      *(short8*)&Vlds[d * 136 + part * 8] =
          *(const short8*)(Vb + (size_t)d * 1024 + c0 + part * 8);
    }
    __syncthreads();
#pragma unroll
    for (int pair = 0; pair < 4; ++pair) {
      short8 kf0 = *(const short8*)&Klds[(pair * 32 + lq) * 40 + quad * 8];
      short8 kf1 = *(const short8*)&Klds[(pair * 32 + 16 + lq) * 40 + quad * 8];
      f32x4 s0 = __builtin_amdgcn_mfma_f32_16x16x32_bf16(kf0, qf, zf, 0, 0, 0);
      f32x4 s1 = __builtin_amdgcn_mfma_f32_16x16x32_bf16(kf1, qf, zf, 0, 0, 0);
      f32x4 e0, e1;
#pragma unroll
      for (int r = 0; r < 4; ++r) {
        e0[r] = exp2f(s0[r]);
        e1[r] = exp2f(s1[r]);
      }
      lsum += (e0[0] + e0[1]) + (e0[2] + e0[3]) +
              (e1[0] + e1[1]) + (e1[2] + e1[3]);
      i32x4 pi;
      pi[0] = (int)pk_trunc(e0[0], e0[1]);
      pi[1] = (int)pk_trunc(e0[2], e0[3]);
      pi[2] = (int)pk_trunc(e1[0], e1[1]);
      pi[3] = (int)pk_trunc(e1[2], e1[3]);
      short8 pf = *(short8*)&pi;
      short8 vf0 = *(const short8*)&Vlds[lq * 136 + pair * 32 + quad * 8];
      short8 vf1 = *(const short8*)&Vlds[(16 + lq) * 136 + pair * 32 + quad * 8];
      O0 = __builtin_amdgcn_mfma_f32_16x16x32_bf16(vf0, pf, O0, 0, 0, 0);
      O1 = __builtin_amdgcn_mfma_f32_16x16x32_bf16(vf1, pf, O1, 0, 0, 0);
    }
  }

  lsum += __shfl_xor(lsum, 16);
  lsum += __shfl_xor(lsum, 32);
  float linv = 1.f / lsum;

  u16x4 pk0, pk1;
#pragma unroll
  for (int r = 0; r < 4; ++r) {
    pk0[r] = f2bf(O0[r] * linv);
    pk1[r] = f2bf(O1[r] * linv);
  }
  u16* crow = ctxB + ((size_t)b * 1024 + myq) * 256 + h * 32 + quad * 4;
  *(u16x4*)crow = pk0;
  *(u16x4*)(crow + 16) = pk1;
  if (quad == 0) linv_ws[(size_t)(b * 8 + h) * 1024 + myq] = linv;
}

// ---------------------------------------------------------------------------
// Colsum (attention map): recompute QK untransposed, p=exp2(s)*linv, reduce
// over queries. grid (8,8,8)=512 blocks, 128q each, 4 waves x 32q.
// ---------------------------------------------------------------------------
__global__ __launch_bounds__(256, 4) void colsum_kernel(
    const u16* __restrict__ QB, const u16* __restrict__ KB,
    const float* __restrict__ linv_ws, float* __restrict__ attn_out) {
  __shared__ __align__(16) u16 Klds[128 * 40];
  __shared__ float colsum[1024];
  int b = blockIdx.z, h = blockIdx.y, q0 = blockIdx.x * 128;
  int t = threadIdx.x, wave = t >> 6, lane = t & 63;
  int lq = lane & 15, quad = lane >> 4;

  const u16* Qb = QB + (size_t)b * 1024 * 256 + h * 32;
  const u16* Kb = KB + (size_t)(b * 8 + h) * 1024 * 32;
  const float* lvp = linv_ws + (size_t)(b * 8 + h) * 1024 + q0 + wave * 32;

  short8 qf2[2];
  f32x4 lv[2];
#pragma unroll
  for (int mt = 0; mt < 2; ++mt) {
    qf2[mt] = *(const short8*)(Qb + (size_t)(q0 + wave * 32 + mt * 16 + lq) * 256 + quad * 8);
    lv[mt] = *(const f32x4*)&lvp[mt * 16 + quad * 4];
  }
  for (int i = t; i < 1024; i += 256) colsum[i] = 0.f;
  const f32x4 zf = (f32x4){0.f, 0.f, 0.f, 0.f};

  for (int c0 = 0; c0 < 1024; c0 += 128) {
    __syncthreads();
    for (int i = t; i < 512; i += 256)
      *(short8*)&Klds[(i >> 2) * 40 + (i & 3) * 8] =
          *(const short8*)(Kb + (size_t)c0 * 32 + i * 8);
    __syncthreads();
#pragma unroll
    for (int nt = 0; nt < 8; ++nt) {
      short8 kf = *(const short8*)&Klds[(nt * 16 + lq) * 40 + quad * 8];
      float cs = 0.f;
#pragma unroll
      for (int mt = 0; mt < 2; ++mt) {
        f32x4 s = __builtin_amdgcn_mfma_f32_16x16x32_bf16(qf2[mt], kf, zf, 0, 0, 0);
        cs += exp2f(s[0]) * lv[mt][0] + exp2f(s[1]) * lv[mt][1] +
              exp2f(s[2]) * lv[mt][2] + exp2f(s[3]) * lv[mt][3];
      }
      cs += __shfl_xor(cs, 16);
      cs += __shfl_xor(cs, 32);
      if (quad == 0) atomicAdd(&colsum[c0 + nt * 16 + lq], cs);
    }
  }
  __syncthreads();
  for (int i = t; i < 1024; i += 256)
    atomicAdd(&attn_out[b * 1024 + i], colsum[i] * (1.f / 8192.f));
}

// ---------------------------------------------------------------------------
// Fused out GEMM + BN + SiLU + residual. Tile 64c x 64s, grid (16,4,8)=512.
// ---------------------------------------------------------------------------
__global__ __launch_bounds__(256, 4) void fused_out(
    const u16* __restrict__ M2B, const u16* __restrict__ ctxB,
    const float* __restrict__ tgt, const float2* __restrict__ bnpk,
    float* __restrict__ y) {
  __shared__ __align__(16) u16 Al[64 * 40];
  __shared__ __align__(16) u16 Bl[64 * 40];
  int b = blockIdx.z, c0 = blockIdx.y * 64, s0 = blockIdx.x * 64;
  int t = threadIdx.x, wave = t >> 6, lane = t & 63;
  int lq = lane & 15, quad = lane >> 4;
  f32x4 acc[4];
#pragma unroll
  for (int mt = 0; mt < 4; ++mt) acc[mt] = (f32x4){0.f, 0.f, 0.f, 0.f};

  for (int k0 = 0; k0 < 256; k0 += 32) {
    __syncthreads();
    {
      int row = t >> 2, seg = t & 3;
      *(short8*)&Al[row * 40 + seg * 8] =
          *(const short8*)&M2B[(size_t)(c0 + row) * 256 + k0 + seg * 8];
      *(short8*)&Bl[row * 40 + seg * 8] =
          *(const short8*)&ctxB[((size_t)b * 1024 + s0 + row) * 256 + k0 + seg * 8];
    }
    __syncthreads();
    short8 bf = *(const short8*)&Bl[(wave * 16 + lq) * 40 + quad * 8];
    short8 af[4];
#pragma unroll
    for (int mt = 0; mt < 4; ++mt)
      af[mt] = *(const short8*)&Al[(mt * 16 + lq) * 40 + quad * 8];
#pragma unroll
    for (int mt = 0; mt < 4; ++mt)
      acc[mt] = __builtin_amdgcn_mfma_f32_16x16x32_bf16(af[mt], bf, acc[mt], 0, 0, 0);
  }
  int s = s0 + wave * 16 + lq;
#pragma unroll
  for (int mt = 0; mt < 4; ++mt) {
#pragma unroll
    for (int r = 0; r < 4; ++r) {
      int c = c0 + mt * 16 + quad * 4 + r;
      float2 p = bnpk[c];
      float bn = acc[mt][r] * p.x + p.y;
      float sig = 1.f / (1.f + __expf(-bn));
      size_t idx = ((size_t)b * 256 + c) * 1024 + s;
      y[idx] = tgt[idx] + bn * sig;
    }
  }
}

// ---------------------------------------------------------------------------
extern "C" void kernel_launch(void* const* d_in, const int* in_sizes, int n_in,
                              void* d_out, int out_size, void* d_ws, size_t ws_size,
                              hipStream_t stream) {
  const float* tgt = (const float*)d_in[0];
  const float* src = (const float*)d_in[1];
  const float* kv_w = (const float*)d_in[2];
  const float* in_proj_w = (const float*)d_in[3];
  const float* in_proj_b = (const float*)d_in[4];
  const float* out_proj_w = (const float*)d_in[5];
  const float* out_proj_b = (const float*)d_in[6];
  const float* fuse_w = (const float*)d_in[7];
  const float* bn_gamma = (const float*)d_in[8];
  const float* bn_beta = (const float*)d_in[9];
  const float* bn_mean = (const float*)d_in[10];
  const float* bn_var = (const float*)d_in[11];

  char* W = (char*)d_ws;
  u16* WqB = (u16*)W;                      // 128KB
  u16* WkvB = (u16*)(W + 131072);          // 128KB
  u16* M2B = (u16*)(W + 262144);           // 128KB
  float* qbias = (float*)(W + 393216);     // 1KB
  float2* bnpk = (float2*)(W + 394240);    // 2KB
  u16* tgtT = (u16*)(W + 397312);          // 4MB (B,S,256) bf16
  u16* srcT = tgtT + 2097152;              // 2MB (B,S,128) bf16
  u16* QB = srcT + 1048576;                // 4MB (B,S,E)
  u16* KB = QB + 2097152;                  // 4MB (B,nH,S,hd)
  u16* VB = KB + 2097152;                  // 4MB (B,E,S)
  u16* ctxB = VB + 2097152;                // 4MB (B,S,E)
  float* linv_ws = (float*)(ctxB + 2097152);  // 256KB (B,nH,S)

  float* y = (float*)d_out;
  float* attn_out = y + 2097152;

  hipMemsetAsync(attn_out, 0, 8192 * sizeof(float), stream);
  prep_kernel<<<769, 256, 0, stream>>>(in_proj_w, in_proj_b, kv_w, fuse_w,
                                       out_proj_w, out_proj_b, bn_gamma, bn_beta,
                                       bn_mean, bn_var, WqB, WkvB, M2B, qbias, bnpk);
  xpose<<<dim3(16, 6, 8), 256, 0, stream>>>(tgt, src, tgtT, srcT);
  qkv_gemm<<<dim3(8, 12, 8), 256, 0, stream>>>(tgtT, srcT, WqB, WkvB, qbias,
                                               in_proj_b + 256, QB, KB, VB);
  attn_passA<<<dim3(16, 8, 8), 256, 0, stream>>>(QB, KB, VB, ctxB, linv_ws);
  colsum_kernel<<<dim3(8, 8, 8), 256, 0, stream>>>(QB, KB, linv_ws, attn_out);
  fused_out<<<dim3(16, 4, 8), 256, 0, stream>>>(M2B, ctxB, tgt, bnpk, y);
}

// Round 7
// 168.005 us; speedup vs baseline: 1.2132x; 1.1030x over previous
//
#include <hip/hip_runtime.h>
#include <hip/hip_bf16.h>

// B=8, Ct=256, Cs=128, H=W=32, S=1024, E=256, nH=8, hd=32
typedef unsigned short u16;
typedef unsigned int u32;
typedef __attribute__((ext_vector_type(8))) short short8;
typedef __attribute__((ext_vector_type(4))) float f32x4;
typedef __attribute__((ext_vector_type(4))) unsigned short u16x4;
typedef __attribute__((ext_vector_type(4))) int i32x4;

static __device__ __forceinline__ u16 f2bf(float x) {
  __hip_bfloat16 b = __float2bfloat16(x);
  return *reinterpret_cast<u16*>(&b);
}
static __device__ __forceinline__ u32 fbits(float x) {
  union { float f; u32 u; } v; v.f = x; return v.u;
}
// pack two f32 -> two truncated bf16 in one dword
static __device__ __forceinline__ u32 pk_trunc(float lo, float hi) {
  return __builtin_amdgcn_perm(fbits(hi), fbits(lo), 0x07060302u);
}
// async global->LDS, 16B per lane; dest = lds base (wave-uniform) + lane*16
static __device__ __forceinline__ void gl2lds16(const u16* g, u16* l) {
  __builtin_amdgcn_global_load_lds(
      (const __attribute__((address_space(1))) void*)g,
      (__attribute__((address_space(3))) void*)l, 16, 0, 0);
}

// 1/sqrt(32) * log2(e)  (exp2-based softmax)
#define QSCALE2 (0.17677669529663687f * 1.4426950408889634f)

// ---------------------------------------------------------------------------
// Merged prep + transpose-cast.
// blocks [0,769): prep: WqB=Wq*qscale2, WkvB=[Wk@kv_w;Wv@kv_w], M2B, qbias, bnpk
// blocks [769,1537): xpose: tgt->tgtT (B,1024,256) bf16, src->srcT (B,1024,128)
// ---------------------------------------------------------------------------
__global__ __launch_bounds__(256) void prep_xpose(
    const float* __restrict__ in_proj_w, const float* __restrict__ in_proj_b,
    const float* __restrict__ kv_w, const float* __restrict__ fuse_w,
    const float* __restrict__ out_proj_w, const float* __restrict__ out_proj_b,
    const float* __restrict__ gamma, const float* __restrict__ beta,
    const float* __restrict__ mean, const float* __restrict__ var,
    const float* __restrict__ tgt, const float* __restrict__ src,
    u16* __restrict__ WqB, u16* __restrict__ WkvB, u16* __restrict__ M2B,
    float* __restrict__ qbias, float2* __restrict__ bnpk,
    u16* __restrict__ tgtT, u16* __restrict__ srcT) {
  if (blockIdx.x < 769) {
    int idx = blockIdx.x * 256 + threadIdx.x;
    if (idx < 65536) {
      WqB[idx] = f2bf(in_proj_w[idx] * QSCALE2);
    } else if (idx < 131072) {
      int i = idx - 65536;
      int m = i >> 7, c = i & 127;
      const float* wrow = in_proj_w + (size_t)(256 + m) * 256;
      float s = 0.f;
      for (int e2 = 0; e2 < 256; ++e2) s += wrow[e2] * kv_w[e2 * 128 + c];
      WkvB[i] = f2bf(s);
    } else if (idx < 196608) {
      int i = idx - 131072;
      int c = i >> 8, e2 = i & 255;
      float s = 0.f;
      for (int e = 0; e < 256; ++e)
        s += fuse_w[c * 256 + e] * out_proj_w[e * 256 + e2];
      M2B[i] = f2bf(s);
    } else if (idx < 196864) {
      int c = idx - 196608;
      float fbv = 0.f;
      for (int e = 0; e < 256; ++e) fbv += fuse_w[c * 256 + e] * out_proj_b[e];
      float inv = gamma[c] * rsqrtf(var[c] + 1e-5f);
      bnpk[c] = make_float2(inv, (fbv - mean[c]) * inv + beta[c]);
      qbias[c] = in_proj_b[c] * QSCALE2;
    }
    return;
  }
  // ---- xpose part ----
  __shared__ u16 tile[64 * 65];
  int i0 = blockIdx.x - 769;
  int b = i0 / 96, rem = i0 % 96;
  int by = rem >> 4, sb = (rem & 15) * 64;
  const float* X;
  u16* XT;
  int C, cb;
  if (by < 4) {
    X = tgt + (size_t)b * 256 * 1024;
    XT = tgtT + (size_t)b * 1024 * 256;
    C = 256;
    cb = by * 64;
  } else {
    X = src + (size_t)b * 128 * 1024;
    XT = srcT + (size_t)b * 1024 * 128;
    C = 128;
    cb = (by - 4) * 64;
  }
  int t = threadIdx.x;
  for (int i = t; i < 4096; i += 256) {
    int c = i >> 6, s = i & 63;
    tile[c * 65 + s] = f2bf(X[(size_t)(cb + c) * 1024 + sb + s]);
  }
  __syncthreads();
  for (int i = t; i < 4096; i += 256) {
    int s = i >> 6, c = i & 63;
    XT[(size_t)(sb + s) * C + cb + c] = tile[c * 65 + s];
  }
}

// ---------------------------------------------------------------------------
// QKV projection, bf16 MFMA, global_load_lds staging (m97 pattern).
// grid (8, 12, 8): my<4 -> Q (WqB, K=256, tgtT); else KV (WkvB, K=128, srcT).
// Tile 64m x 128n; wave = 64m x 32n (acc 4x2). LDS unpadded [row][32] bf16.
// ---------------------------------------------------------------------------
__global__ __launch_bounds__(256, 4) void qkv_gemm(
    const u16* __restrict__ tgtT, const u16* __restrict__ srcT,
    const u16* __restrict__ WqB, const u16* __restrict__ WkvB,
    const float* __restrict__ qbias, const float* __restrict__ bkv,
    u16* __restrict__ QB, u16* __restrict__ KB, u16* __restrict__ VB) {
  __shared__ __align__(16) u16 Wl[64 * 32];   // 4KB
  __shared__ __align__(16) u16 Xl[128 * 32];  // 8KB
  int b = blockIdx.z, my = blockIdx.y, n0 = blockIdx.x * 128;
  bool isQ = my < 4;
  int m0 = isQ ? my * 64 : (my - 4) * 64;
  int Kd = isQ ? 256 : 128;
  const u16* Wp = isQ ? WqB : WkvB;
  const u16* Xp = isQ ? tgtT + (size_t)b * 1024 * 256
                      : srcT + (size_t)b * 1024 * 128;
  int t = threadIdx.x, wave = t >> 6, lane = t & 63;
  int lq = lane & 15, quad = lane >> 4;
  int srow = t >> 2, sseg = t & 3;  // staging row/segment
  f32x4 acc[4][2];
#pragma unroll
  for (int mt = 0; mt < 4; ++mt)
#pragma unroll
    for (int nt = 0; nt < 2; ++nt) acc[mt][nt] = (f32x4){0.f, 0.f, 0.f, 0.f};

  for (int k0 = 0; k0 < Kd; k0 += 32) {
    __syncthreads();
    // W tile 64x32: one 16B op/thread
    gl2lds16(&Wp[(size_t)(m0 + srow) * Kd + k0 + sseg * 8], &Wl[wave * 512]);
    // X tile 128x32: two 16B ops/thread
    gl2lds16(&Xp[(size_t)(n0 + srow) * Kd + k0 + sseg * 8], &Xl[wave * 512]);
    gl2lds16(&Xp[(size_t)(n0 + 64 + srow) * Kd + k0 + sseg * 8],
             &Xl[2048 + wave * 512]);
    __syncthreads();
    short8 af[4], bf[2];
#pragma unroll
    for (int mt = 0; mt < 4; ++mt)
      af[mt] = *(const short8*)&Wl[(mt * 16 + lq) * 32 + quad * 8];
#pragma unroll
    for (int nt = 0; nt < 2; ++nt)
      bf[nt] = *(const short8*)&Xl[(wave * 32 + nt * 16 + lq) * 32 + quad * 8];
#pragma unroll
    for (int mt = 0; mt < 4; ++mt)
#pragma unroll
      for (int nt = 0; nt < 2; ++nt)
        acc[mt][nt] = __builtin_amdgcn_mfma_f32_16x16x32_bf16(af[mt], bf[nt],
                                                              acc[mt][nt], 0, 0, 0);
  }
  if (isQ) {
#pragma unroll
    for (int mt = 0; mt < 4; ++mt) {
      int e = m0 + mt * 16 + quad * 4;
      f32x4 bi = *(const f32x4*)&qbias[e];
#pragma unroll
      for (int nt = 0; nt < 2; ++nt) {
        int n = n0 + wave * 32 + nt * 16 + lq;
        u16x4 pk;
#pragma unroll
        for (int r = 0; r < 4; ++r) pk[r] = f2bf(acc[mt][nt][r] + bi[r]);
        *(u16x4*)&QB[((size_t)b * 1024 + n) * 256 + e] = pk;
      }
    }
  } else {
#pragma unroll
    for (int mt = 0; mt < 4; ++mt) {
      int m = m0 + mt * 16 + quad * 4;
      f32x4 bi = *(const f32x4*)&bkv[m];
#pragma unroll
      for (int nt = 0; nt < 2; ++nt) {
        int n = n0 + wave * 32 + nt * 16 + lq;
        if (m < 256) {
          int hh = m >> 5, d = m & 31;
          u16x4 pk;
#pragma unroll
          for (int r = 0; r < 4; ++r) pk[r] = f2bf(acc[mt][nt][r] + bi[r]);
          *(u16x4*)&KB[((size_t)(b * 8 + hh) * 1024 + n) * 32 + d] = pk;
        } else {
          int e = m - 256;
#pragma unroll
          for (int r = 0; r < 4; ++r)
            VB[((size_t)b * 256 + e + r) * 1024 + n] = f2bf(acc[mt][nt][r] + bi[r]);
        }
      }
    }
  }
}

// ---------------------------------------------------------------------------
// Attention pass A (register-P, transposed scores) with global_load_lds K/V.
// K staged LINEAR (unpadded [key][32]); the key permutation is applied at
// frag-read: kf0 row = pair*32+keyA, kf1 = +4, keyA = ((lq>>2)<<3)|(lq&3)
// (validated in R5). V staged in 8 groups of 4 d-rows with 1088B group stride
// (64B inter-group pad keeps bank phases spread).
// grid (16,8,8)=1024 blocks, 64q, 4 waves x 16q.
// ---------------------------------------------------------------------------
__global__ __launch_bounds__(256, 4) void attn_passA(
    const u16* __restrict__ QB, const u16* __restrict__ KB,
    const u16* __restrict__ VB, u16* __restrict__ ctxB,
    float* __restrict__ linv_ws) {
  __shared__ __align__(16) u16 Klds[128 * 32];  // 8KB, linear rows
  __shared__ __align__(16) u16 Vlds[8 * 544];   // 8.5KB: group g row d=g*4+(lane>>4)
  int b = blockIdx.z, h = blockIdx.y, q0 = blockIdx.x * 64;
  int t = threadIdx.x, wave = t >> 6, lane = t & 63;
  int lq = lane & 15, quad = lane >> 4;
  int srow = t >> 2, sseg = t & 3;

  const u16* Qb = QB + (size_t)b * 1024 * 256 + h * 32;
  const u16* Kb = KB + (size_t)(b * 8 + h) * 1024 * 32;
  const u16* Vb = VB + (size_t)(b * 256 + h * 32) * 1024;

  int myq = q0 + wave * 16 + lq;
  short8 qf = *(const short8*)(Qb + (size_t)myq * 256 + quad * 8);

  const f32x4 zf = (f32x4){0.f, 0.f, 0.f, 0.f};
  f32x4 O0 = zf, O1 = zf;
  float lsum = 0.f;
  int keyA = ((lq >> 2) << 3) | (lq & 3);

  for (int c0 = 0; c0 < 1024; c0 += 128) {
    __syncthreads();
    // K: 128 rows x 64B, 2 calls/thread
    gl2lds16(Kb + (size_t)(c0 + srow) * 32 + sseg * 8, &Klds[wave * 512]);
    gl2lds16(Kb + (size_t)(c0 + 64 + srow) * 32 + sseg * 8, &Klds[2048 + wave * 512]);
    // V: group g = c*4 + wave covers d-rows g*4+(lane>>4), 16B part (lane&15)
#pragma unroll
    for (int c = 0; c < 2; ++c) {
      int g = c * 4 + wave;
      int d = g * 4 + (lane >> 4);
      gl2lds16(Vb + (size_t)d * 1024 + c0 + (lane & 15) * 8, &Vlds[g * 544]);
    }
    __syncthreads();
#pragma unroll
    for (int pair = 0; pair < 4; ++pair) {
      short8 kf0 = *(const short8*)&Klds[(pair * 32 + keyA) * 32 + quad * 8];
      short8 kf1 = *(const short8*)&Klds[(pair * 32 + keyA + 4) * 32 + quad * 8];
      f32x4 s0 = __builtin_amdgcn_mfma_f32_16x16x32_bf16(kf0, qf, zf, 0, 0, 0);
      f32x4 s1 = __builtin_amdgcn_mfma_f32_16x16x32_bf16(kf1, qf, zf, 0, 0, 0);
      f32x4 e0, e1;
#pragma unroll
      for (int r = 0; r < 4; ++r) {
        e0[r] = exp2f(s0[r]);
        e1[r] = exp2f(s1[r]);
      }
      lsum += (e0[0] + e0[1]) + (e0[2] + e0[3]) +
              (e1[0] + e1[1]) + (e1[2] + e1[3]);
      i32x4 pi;
      pi[0] = (int)pk_trunc(e0[0], e0[1]);
      pi[1] = (int)pk_trunc(e0[2], e0[3]);
      pi[2] = (int)pk_trunc(e1[0], e1[1]);
      pi[3] = (int)pk_trunc(e1[2], e1[3]);
      short8 pf = *(short8*)&pi;
      // V frag: d-row d -> Vlds[(d>>2)*544 + (d&3)*128 + pair*32 + quad*8]
      short8 vf0 = *(const short8*)&Vlds[((lq >> 2) * 544) + (lq & 3) * 128 +
                                         pair * 32 + quad * 8];
      short8 vf1 = *(const short8*)&Vlds[((4 + (lq >> 2)) * 544) + (lq & 3) * 128 +
                                         pair * 32 + quad * 8];
      O0 = __builtin_amdgcn_mfma_f32_16x16x32_bf16(vf0, pf, O0, 0, 0, 0);
      O1 = __builtin_amdgcn_mfma_f32_16x16x32_bf16(vf1, pf, O1, 0, 0, 0);
    }
  }

  lsum += __shfl_xor(lsum, 16);
  lsum += __shfl_xor(lsum, 32);
  float linv = 1.f / lsum;

  u16x4 pk0, pk1;
#pragma unroll
  for (int r = 0; r < 4; ++r) {
    pk0[r] = f2bf(O0[r] * linv);
    pk1[r] = f2bf(O1[r] * linv);
  }
  u16* crow = ctxB + ((size_t)b * 1024 + myq) * 256 + h * 32 + quad * 4;
  *(u16x4*)crow = pk0;
  *(u16x4*)(crow + 16) = pk1;
  if (quad == 0) linv_ws[(size_t)(b * 8 + h) * 1024 + myq] = linv;
}

// ---------------------------------------------------------------------------
// Colsum (attention map): recompute QK untransposed, p=exp2(s)*linv, reduce
// over queries. grid (8,8,8)=512 blocks, 128q each, 4 waves x 32q.
// ---------------------------------------------------------------------------
__global__ __launch_bounds__(256, 4) void colsum_kernel(
    const u16* __restrict__ QB, const u16* __restrict__ KB,
    const float* __restrict__ linv_ws, float* __restrict__ attn_out) {
  __shared__ __align__(16) u16 Klds[128 * 32];  // 8KB linear
  __shared__ float colsum[1024];
  int b = blockIdx.z, h = blockIdx.y, q0 = blockIdx.x * 128;
  int t = threadIdx.x, wave = t >> 6, lane = t & 63;
  int lq = lane & 15, quad = lane >> 4;
  int srow = t >> 2, sseg = t & 3;

  const u16* Qb = QB + (size_t)b * 1024 * 256 + h * 32;
  const u16* Kb = KB + (size_t)(b * 8 + h) * 1024 * 32;
  const float* lvp = linv_ws + (size_t)(b * 8 + h) * 1024 + q0 + wave * 32;

  short8 qf2[2];
  f32x4 lv[2];
#pragma unroll
  for (int mt = 0; mt < 2; ++mt) {
    qf2[mt] = *(const short8*)(Qb + (size_t)(q0 + wave * 32 + mt * 16 + lq) * 256 + quad * 8);
    lv[mt] = *(const f32x4*)&lvp[mt * 16 + quad * 4];
  }
  for (int i = t; i < 1024; i += 256) colsum[i] = 0.f;
  const f32x4 zf = (f32x4){0.f, 0.f, 0.f, 0.f};

  for (int c0 = 0; c0 < 1024; c0 += 128) {
    __syncthreads();
    gl2lds16(Kb + (size_t)(c0 + srow) * 32 + sseg * 8, &Klds[wave * 512]);
    gl2lds16(Kb + (size_t)(c0 + 64 + srow) * 32 + sseg * 8, &Klds[2048 + wave * 512]);
    __syncthreads();
#pragma unroll
    for (int nt = 0; nt < 8; ++nt) {
      short8 kf = *(const short8*)&Klds[(nt * 16 + lq) * 32 + quad * 8];
      float cs = 0.f;
#pragma unroll
      for (int mt = 0; mt < 2; ++mt) {
        f32x4 s = __builtin_amdgcn_mfma_f32_16x16x32_bf16(qf2[mt], kf, zf, 0, 0, 0);
        cs += exp2f(s[0]) * lv[mt][0] + exp2f(s[1]) * lv[mt][1] +
              exp2f(s[2]) * lv[mt][2] + exp2f(s[3]) * lv[mt][3];
      }
      cs += __shfl_xor(cs, 16);
      cs += __shfl_xor(cs, 32);
      if (quad == 0) atomicAdd(&colsum[c0 + nt * 16 + lq], cs);
    }
  }
  __syncthreads();
  for (int i = t; i < 1024; i += 256)
    atomicAdd(&attn_out[b * 1024 + i], colsum[i] * (1.f / 8192.f));
}

// ---------------------------------------------------------------------------
// Fused out GEMM + BN + SiLU + residual, global_load_lds staging.
// Tile 64c x 64s, grid (16,4,8)=512.
// ---------------------------------------------------------------------------
__global__ __launch_bounds__(256, 4) void fused_out(
    const u16* __restrict__ M2B, const u16* __restrict__ ctxB,
    const float* __restrict__ tgt, const float2* __restrict__ bnpk,
    float* __restrict__ y) {
  __shared__ __align__(16) u16 Al[64 * 32];  // 4KB
  __shared__ __align__(16) u16 Bl[64 * 32];  // 4KB
  int b = blockIdx.z, c0 = blockIdx.y * 64, s0 = blockIdx.x * 64;
  int t = threadIdx.x, wave = t >> 6, lane = t & 63;
  int lq = lane & 15, quad = lane >> 4;
  int srow = t >> 2, sseg = t & 3;
  f32x4 acc[4];
#pragma unroll
  for (int mt = 0; mt < 4; ++mt) acc[mt] = (f32x4){0.f, 0.f, 0.f, 0.f};

  for (int k0 = 0; k0 < 256; k0 += 32) {
    __syncthreads();
    gl2lds16(&M2B[(size_t)(c0 + srow) * 256 + k0 + sseg * 8], &Al[wave * 512]);
    gl2lds16(&ctxB[((size_t)b * 1024 + s0 + srow) * 256 + k0 + sseg * 8],
             &Bl[wave * 512]);
    __syncthreads();
    short8 bf = *(const short8*)&Bl[(wave * 16 + lq) * 32 + quad * 8];
    short8 af[4];
#pragma unroll
    for (int mt = 0; mt < 4; ++mt)
      af[mt] = *(const short8*)&Al[(mt * 16 + lq) * 32 + quad * 8];
#pragma unroll
    for (int mt = 0; mt < 4; ++mt)
      acc[mt] = __builtin_amdgcn_mfma_f32_16x16x32_bf16(af[mt], bf, acc[mt], 0, 0, 0);
  }
  int s = s0 + wave * 16 + lq;
#pragma unroll
  for (int mt = 0; mt < 4; ++mt) {
#pragma unroll
    for (int r = 0; r < 4; ++r) {
      int c = c0 + mt * 16 + quad * 4 + r;
      float2 p = bnpk[c];
      float bn = acc[mt][r] * p.x + p.y;
      float sig = 1.f / (1.f + __expf(-bn));
      size_t idx = ((size_t)b * 256 + c) * 1024 + s;
      y[idx] = tgt[idx] + bn * sig;
    }
  }
}

// ---------------------------------------------------------------------------
extern "C" void kernel_launch(void* const* d_in, const int* in_sizes, int n_in,
                              void* d_out, int out_size, void* d_ws, size_t ws_size,
                              hipStream_t stream) {
  const float* tgt = (const float*)d_in[0];
  const float* src = (const float*)d_in[1];
  const float* kv_w = (const float*)d_in[2];
  const float* in_proj_w = (const float*)d_in[3];
  const float* in_proj_b = (const float*)d_in[4];
  const float* out_proj_w = (const float*)d_in[5];
  const float* out_proj_b = (const float*)d_in[6];
  const float* fuse_w = (const float*)d_in[7];
  const float* bn_gamma = (const float*)d_in[8];
  const float* bn_beta = (const float*)d_in[9];
  const float* bn_mean = (const float*)d_in[10];
  const float* bn_var = (const float*)d_in[11];

  char* W = (char*)d_ws;
  u16* WqB = (u16*)W;                      // 128KB
  u16* WkvB = (u16*)(W + 131072);          // 128KB
  u16* M2B = (u16*)(W + 262144);           // 128KB
  float* qbias = (float*)(W + 393216);     // 1KB
  float2* bnpk = (float2*)(W + 394240);    // 2KB
  u16* tgtT = (u16*)(W + 397312);          // 4MB (B,S,256) bf16
  u16* srcT = tgtT + 2097152;              // 2MB (B,S,128) bf16
  u16* QB = srcT + 1048576;                // 4MB (B,S,E)
  u16* KB = QB + 2097152;                  // 4MB (B,nH,S,hd)
  u16* VB = KB + 2097152;                  // 4MB (B,E,S)
  u16* ctxB = VB + 2097152;                // 4MB (B,S,E)
  float* linv_ws = (float*)(ctxB + 2097152);  // 256KB (B,nH,S)

  float* y = (float*)d_out;
  float* attn_out = y + 2097152;

  hipMemsetAsync(attn_out, 0, 8192 * sizeof(float), stream);
  prep_xpose<<<1537, 256, 0, stream>>>(in_proj_w, in_proj_b, kv_w, fuse_w,
                                       out_proj_w, out_proj_b, bn_gamma, bn_beta,
                                       bn_mean, bn_var, tgt, src,
                                       WqB, WkvB, M2B, qbias, bnpk, tgtT, srcT);
  qkv_gemm<<<dim3(8, 12, 8), 256, 0, stream>>>(tgtT, srcT, WqB, WkvB, qbias,
                                               in_proj_b + 256, QB, KB, VB);
  attn_passA<<<dim3(16, 8, 8), 256, 0, stream>>>(QB, KB, VB, ctxB, linv_ws);
  colsum_kernel<<<dim3(8, 8, 8), 256, 0, stream>>>(QB, KB, linv_ws, attn_out);
  fused_out<<<dim3(16, 4, 8), 256, 0, stream>>>(M2B, ctxB, tgt, bnpk, y);
}